// Round 14
// baseline (270.129 us; speedup 1.0000x reference)
//
#include <hip/hip_runtime.h>
#include <hip/hip_bf16.h>
#include <cstdint>
#include <cmath>

// B=4, L=2048, D=1024, H=16, DK=64
// Pipeline: f32->bf16 converts, mask bitpack, GEMM1 (QKV proj, Q pre-scaled by
// 0.125*log2e, V written transposed), flash-attention (8-wave blocks,
// LDS-staged K/V, swapped QK^T, fixed m=0 softmax in log2 domain via exp2f,
// ones-MFMA denom), GEMM2 (+b2, f32 out).
// SINGLE DELTA vs R13 (green, 246.5us): Q scale 0.125 -> 0.125*log2e and
// __expf -> exp2f (libm, lowers to raw v_exp_f32; removes 16 v_mul/tile).
// Masked score stays exact 0.0 -> exp2(0)=1 in denominator (torch quirk OK).
// Masking stays the PROVEN select form (AND-mask convicted R9).

typedef __attribute__((ext_vector_type(4))) float f32x4;
typedef __attribute__((ext_vector_type(8))) short s16x8;
typedef __attribute__((ext_vector_type(4))) short s16x4;
typedef __attribute__((ext_vector_type(4))) int   i32x4;

#define AS1 __attribute__((address_space(1)))
#define AS3 __attribute__((address_space(3)))

__device__ __forceinline__ short f2bf(float x) {
  unsigned u = __builtin_bit_cast(unsigned, x);
  unsigned r = u + 0x7fffu + ((u >> 16) & 1u);   // RNE
  return (short)(r >> 16);
}
__device__ __forceinline__ unsigned pack2(float a, float b) {
  // compiler-owned bf16x2 conversion; .x = low word, .y = high word.
  __hip_bfloat162 v = __float22bfloat162_rn(make_float2(a, b));
  unsigned r;
  __builtin_memcpy(&r, &v, 4);
  return r;
}

// ---------------- f32 -> bf16 elementwise (4/thread) ----------------
__global__ __launch_bounds__(256) void k_convert(const float* __restrict__ in,
                                                 short* __restrict__ out, int n4) {
  int i = blockIdx.x * 256 + threadIdx.x;
  if (i >= n4) return;
  float4 v = ((const float4*)in)[i];
  s16x4 o;
  o[0] = f2bf(v.x); o[1] = f2bf(v.y); o[2] = f2bf(v.z); o[3] = f2bf(v.w);
  ((s16x4*)out)[i] = o;
}

// ---------- transpose + convert: in (R x C) f32 -> out (C x R) bf16 ----------
__global__ __launch_bounds__(256) void k_transpose(const float* __restrict__ in,
                                                   short* __restrict__ out, int R, int C) {
  __shared__ float tile[32][33];
  int c0 = blockIdx.x * 32, r0 = blockIdx.y * 32;
  int tx = threadIdx.x, ty = threadIdx.y;     // block (32,8)
  #pragma unroll
  for (int k = 0; k < 32; k += 8)
    tile[ty + k][tx] = in[(size_t)(r0 + ty + k) * C + c0 + tx];
  __syncthreads();
  #pragma unroll
  for (int k = 0; k < 32; k += 8)
    out[(size_t)(c0 + ty + k) * R + r0 + tx] = f2bf(tile[tx][ty + k]);
}

// ---------------- mask (int32 0/1) -> bitmask via ballot ----------------
__global__ __launch_bounds__(256) void k_maskpack(const int* __restrict__ mask,
                                                  unsigned* __restrict__ bits) {
  int i = blockIdx.x * 256 + threadIdx.x;
  unsigned long long bal = __ballot(mask[i] != 0);
  int lane = threadIdx.x & 63;
  if (lane == 0)       bits[i >> 5] = (unsigned)bal;
  else if (lane == 32) bits[i >> 5] = (unsigned)(bal >> 32);
}

// ---------------- bf16 MFMA GEMM, A (MxK) row-major, Bt (NxK) row-major ------
// MODE 0: QKV projection -> bf16 out; cols <1024 (Q) scaled by 0.125*log2e,
//         cols <2048 to QKbuf, cols >=2048 to Vt transposed.
// MODE 1: output projection -> f32 out (d_out), +bias.
// Staging: global_load_lds width=16, pre-swizzled source chunk (attn-proven),
// double-buffered STAGE(next)->compute(cur)->barrier schedule.
template <int MODE>
__global__ __launch_bounds__(256, 2) void k_gemm(
    const short* __restrict__ A, const short* __restrict__ Bt,
    const float* __restrict__ bias,
    short* __restrict__ outQK, short* __restrict__ outVt,
    float* __restrict__ outF, int K, int N) {
  __shared__ short Ast[2][128 * 64];
  __shared__ short Bst[2][128 * 64];
  const int tid = threadIdx.x;
  const int lane = tid & 63;
  const int wv = tid >> 6;
  const int g = lane >> 4, c = lane & 15;
  const int m0 = blockIdx.x * 128, n0 = blockIdx.y * 128;
  const int wm = (wv & 1) * 64, wn = (wv >> 1) * 64;

  // staging: wave wv, iter p stages rows [p*32 + wv*8, +8); row&7 == rsub
  const int rsub = lane >> 3;                    // 0..7
  const int cp = (lane & 7) ^ rsub;              // pre-swizzled source chunk
  const short* aSrc = A  + (size_t)(m0 + wv * 8 + rsub) * K + cp * 8;
  const short* bSrc = Bt + (size_t)(n0 + wv * 8 + rsub) * K + cp * 8;

  auto STAGE = [&](int buf, int kt) {
    #pragma unroll
    for (int p = 0; p < 4; ++p) {
      __builtin_amdgcn_global_load_lds(
          (const AS1 void*)(aSrc + (size_t)(p * 32) * K + kt * 64),
          (AS3 void*)&Ast[buf][(p * 32 + wv * 8) * 64], 16, 0, 0);
      __builtin_amdgcn_global_load_lds(
          (const AS1 void*)(bSrc + (size_t)(p * 32) * K + kt * 64),
          (AS3 void*)&Bst[buf][(p * 32 + wv * 8) * 64], 16, 0, 0);
    }
  };

  f32x4 acc[4][4] = {};

  const int nkt = K >> 6;
  STAGE(0, 0);
  __syncthreads();

  #pragma unroll 1
  for (int kt = 0; kt < nkt; ++kt) {
    const int cur = kt & 1;
    if (kt + 1 < nkt) STAGE(cur ^ 1, kt + 1);
    #pragma unroll
    for (int s = 0; s < 2; ++s) {
      s16x8 aF[4], bF[4];
      #pragma unroll
      for (int mi = 0; mi < 4; ++mi) {
        int row = wm + mi * 16 + c;
        aF[mi] = *(const s16x8*)((const char*)&Ast[cur][0] + row * 128 +
                                 ((s * 64 + g * 16) ^ ((row & 7) << 4)));
      }
      #pragma unroll
      for (int ni = 0; ni < 4; ++ni) {
        int row = wn + ni * 16 + c;
        bF[ni] = *(const s16x8*)((const char*)&Bst[cur][0] + row * 128 +
                                 ((s * 64 + g * 16) ^ ((row & 7) << 4)));
      }
      #pragma unroll
      for (int mi = 0; mi < 4; ++mi)
        #pragma unroll
        for (int ni = 0; ni < 4; ++ni)
          acc[mi][ni] = __builtin_amdgcn_mfma_f32_16x16x32_bf16(
              aF[mi], bF[ni], acc[mi][ni], 0, 0, 0);
    }
    __syncthreads();   // drains vmcnt (next tile staged) + all waves done with cur
  }

  #pragma unroll
  for (int mi = 0; mi < 4; ++mi) {
    #pragma unroll
    for (int ni = 0; ni < 4; ++ni) {
      int colg = n0 + wn + ni * 16 + c;
      float bv = bias[colg];
      int rbase = m0 + wm + mi * 16 + 4 * g;   // 4 consecutive rows (4-aligned)
      if (MODE == 0) {
        // fold 1/sqrt(dk) * log2(e) into Q so attn uses exp2f directly
        float sc = (colg < 1024) ? 0.125f * 1.44269504088896340736f : 1.0f;
        if (colg < 2048) {
          #pragma unroll
          for (int r = 0; r < 4; ++r)
            outQK[(size_t)(rbase + r) * 2048 + colg] = f2bf((acc[mi][ni][r] + bv) * sc);
        } else {
          int j = colg - 2048;             // h*64+dk
          int bb = rbase >> 11, lq = rbase & 2047;
          s16x4 pk;
          #pragma unroll
          for (int r = 0; r < 4; ++r) pk[r] = f2bf(acc[mi][ni][r] + bv);
          *(s16x4*)(outVt + (size_t)((bb << 10) + j) * 2048 + lq) = pk;
        }
      } else {
        #pragma unroll
        for (int r = 0; r < 4; ++r)
          outF[(size_t)(rbase + r) * N + colg] = acc[mi][ni][r] + bv;
      }
    }
  }
}

// ---------------- flash attention: 8-wave blocks, shared K/V staging ---------
// Grid (L/128, H, B), 8 waves x 16 q-rows = 128 q-rows/block. K/V tiles staged
// double-buffered via global_load_lds (pre-swizzled source, rule #21); wave wv
// stages rows [wv*8, wv*8+8) = 1 instruction per buffer. S^T = mfma(K,Q):
// lane (c,g) holds S[q=c][k=16t+4g+r], scores in log2 units (Q pre-scaled).
// Fixed m=0 softmax; p_num = bt ? exp2f(s) : 0 (select form). Denominator =
// ones-MFMA rowsum + popcount(masked) (each masked key contributes exp2(0)=1).
__global__ __launch_bounds__(512) void k_attn(
    const short* __restrict__ QK, const short* __restrict__ Vt,
    const unsigned* __restrict__ mbits, short* __restrict__ ctxb) {
  __shared__ short Klds[2][64 * 64];
  __shared__ short Vlds[2][64 * 64];
  __shared__ short Plds[8][16 * 64];
  const int tid = threadIdx.x;
  const int lane = tid & 63, wv = tid >> 6;      // wv = 0..7
  const int g = lane >> 4, c = lane & 15;
  const int b = blockIdx.z, h = blockIdx.y;
  const int qr = blockIdx.x * 128 + wv * 16;

  // staging: wave wv stages rows [wv*8, wv*8+8) of each tile (row&7 == rsub)
  const int r0 = wv * 8;
  const int rsub = lane >> 3;                    // 0..7
  const int cp = (lane & 7) ^ rsub;              // pre-swizzled source chunk
  const short* kSrc = QK + (size_t)(b * 2048 + r0 + rsub) * 2048 + 1024 + h * 64 + cp * 8;
  const short* vSrc = Vt + (size_t)((b * 16 + h) * 64 + r0 + rsub) * 2048 + cp * 8;

  auto STAGE = [&](int buf, int k0) {
    __builtin_amdgcn_global_load_lds((const AS1 void*)(kSrc + (size_t)k0 * 2048),
        (AS3 void*)&Klds[buf][r0 * 64], 16, 0, 0);
    __builtin_amdgcn_global_load_lds((const AS1 void*)(vSrc + k0),
        (AS3 void*)&Vlds[buf][r0 * 64], 16, 0, 0);
  };

  s16x8 qf[2];                                    // Q = B-operand fragments
  #pragma unroll
  for (int s = 0; s < 2; ++s)
    qf[s] = *(const s16x8*)(QK + (size_t)(b * 2048 + qr + c) * 2048 +
                            h * 64 + s * 32 + g * 8);

  const unsigned* mptr = mbits + (size_t)(b * 2048 + qr + c) * 64;

  // all-ones bf16 B-operand for the rowsum MFMA
  s16x8 ones;
  #pragma unroll
  for (int i = 0; i < 8; ++i) ones[i] = (short)0x3F80;

  int nm = 0;                       // masked count for q-row c (accumulated)
  f32x4 acc[4] = {};                // ctx[q=4g+r][d=16t+c]
  f32x4 accs = {};                  // rowsum[q=4g+r] of bf16 P (all c equal)
  char* pbase = (char*)&Plds[wv][0];
  const int sw = (c & 7) << 4;

  STAGE(0, 0);
  __syncthreads();

  #pragma unroll 1
  for (int it = 0; it < 32; ++it) {
    const int cur = it & 1;
    const int k0 = it * 64;
    if (it < 31) STAGE(cur ^ 1, k0 + 64);

    // ---- S^T = K Q^T : sf[t][r] = S[q=c][k=16t+4g+r] (log2 units) ----
    const char* kb = (const char*)&Klds[cur][0];
    f32x4 sf[4] = {};
    __builtin_amdgcn_s_setprio(1);
    #pragma unroll
    for (int t = 0; t < 4; ++t)
      #pragma unroll
      for (int s = 0; s < 2; ++s) {
        s16x8 kf = *(const s16x8*)(kb + (16 * t + c) * 128 + ((g * 16 + s * 64) ^ sw));
        sf[t] = __builtin_amdgcn_mfma_f32_16x16x32_bf16(kf, qf[s], sf[t], 0, 0, 0);
      }
    __builtin_amdgcn_s_setprio(0);

    // ---- mask bits for this lane's q-row (q = c) ----
    uint2 wd = *(const uint2*)(mptr + (k0 >> 5));
    nm += 64 - __popc(wd.x) - __popc(wd.y);      // masked keys this tile
    unsigned w0 = wd.x >> (4 * g), w1 = wd.y >> (4 * g);
    // ---- p_num = bt ? exp2(s) : 0 ; masked handled via nm in denominator ----
    #pragma unroll
    for (int t = 0; t < 4; ++t) {
      unsigned w = (t < 2) ? w0 : w1;
      int sh = 16 * (t & 1);
      float p[4];
      #pragma unroll
      for (int r = 0; r < 4; ++r) {
        unsigned bt = (w >> (sh + r)) & 1u;
        p[r] = bt ? exp2f(sf[t][r]) : 0.0f;      // masked -> 0 in numerator
      }
      unsigned lo = pack2(p[0], p[1]);
      unsigned hi = pack2(p[2], p[3]);
      *(uint2*)(pbase + c * 128 + ((t * 32 + g * 8) ^ sw)) = make_uint2(lo, hi);
    }
    asm volatile("" ::: "memory");   // keep P writes before P reads
    // ---- ctx += P V ; denom += P ones ----
    s16x8 pa[2];
    #pragma unroll
    for (int s = 0; s < 2; ++s)
      pa[s] = *(const s16x8*)(pbase + c * 128 + ((s * 64 + g * 16) ^ sw));
    const char* vb = (const char*)&Vlds[cur][0];
    __builtin_amdgcn_s_setprio(1);
    accs = __builtin_amdgcn_mfma_f32_16x16x32_bf16(pa[0], ones, accs, 0, 0, 0);
    accs = __builtin_amdgcn_mfma_f32_16x16x32_bf16(pa[1], ones, accs, 0, 0, 0);
    #pragma unroll
    for (int t = 0; t < 4; ++t)
      #pragma unroll
      for (int s = 0; s < 2; ++s) {
        s16x8 vf = *(const s16x8*)(vb + (16 * t + c) * 128 + ((g * 16 + s * 64) ^ sw));
        acc[t] = __builtin_amdgcn_mfma_f32_16x16x32_bf16(pa[s], vf, acc[t], 0, 0, 0);
      }
    __builtin_amdgcn_s_setprio(0);
    __syncthreads();   // drains vmcnt (next tile staged) + all waves done with cur
  }

  // ---- epilogue: denom[q=4g+r] = accs[r] + nm(from lane q=4g+r) ----
  float nmf = (float)nm;
  float lv[4];
  #pragma unroll
  for (int r = 0; r < 4; ++r)
    lv[r] = 1.0f / (accs[r] + __shfl(nmf, 4 * g + r));
  #pragma unroll
  for (int t = 0; t < 4; ++t)
    #pragma unroll
    for (int r = 0; r < 4; ++r)
      ctxb[(size_t)(b * 2048 + qr + 4 * g + r) * 1024 + h * 64 + t * 16 + c] =
          f2bf(acc[t][r] * lv[r]);
}

extern "C" void kernel_launch(void* const* d_in, const int* in_sizes, int n_in,
                              void* d_out, int out_size, void* d_ws, size_t ws_size,
                              hipStream_t stream) {
  const float* inputs = (const float*)d_in[0];   // (4,2048,1024) f32
  const int*   mask   = (const int*)  d_in[1];   // (4,2048,2048) int32
  const float* W1     = (const float*)d_in[2];   // (1024,3072) f32
  const float* b1     = (const float*)d_in[3];   // (3072,) f32
  const float* W2     = (const float*)d_in[4];   // (1024,1024) f32
  const float* b2     = (const float*)d_in[5];   // (1024,) f32
  float* out = (float*)d_out;                    // (4,2048,1024) f32

  char* ws = (char*)d_ws;
  short* Xbf = (short*)ws;        ws += (size_t)8192 * 1024 * 2;   // 16.78 MB
  short* W1t = (short*)ws;        ws += (size_t)3072 * 1024 * 2;   //  6.29 MB
  short* W2t = (short*)ws;        ws += (size_t)1024 * 1024 * 2;   //  2.10 MB
  short* QKb = (short*)ws;        ws += (size_t)8192 * 2048 * 2;   // 33.55 MB
  short* Vtb = (short*)ws;        ws += (size_t)4096 * 2048 * 2;   // 16.78 MB
  short* Ctx = (short*)ws;        ws += (size_t)8192 * 1024 * 2;   // 16.78 MB
  unsigned* mbits = (unsigned*)ws; ws += (size_t)4 * 2048 * 64 * 4; // 2.10 MB
  // total ~94.4 MB of d_ws

  k_convert<<<8192, 256, 0, stream>>>(inputs, Xbf, 2097152);
  k_transpose<<<dim3(96, 32), dim3(32, 8), 0, stream>>>(W1, W1t, 1024, 3072);
  k_transpose<<<dim3(32, 32), dim3(32, 8), 0, stream>>>(W2, W2t, 1024, 1024);
  k_gemm<0><<<dim3(64, 24), 256, 0, stream>>>(Xbf, W1t, b1, QKb, Vtb, nullptr,
                                              1024, 3072);
  k_maskpack<<<65536, 256, 0, stream>>>(mask, mbits);
  k_attn<<<dim3(16, 16, 4), 512, 0, stream>>>(QKb, Vtb, mbits, Ctx);
  k_gemm<1><<<dim3(64, 8), 256, 0, stream>>>(Ctx, W2t, b2, nullptr, nullptr, out,
                                             1024, 1024);
}

// Round 15
// 246.600 us; speedup vs baseline: 1.0954x; 1.0954x over previous
//
#include <hip/hip_runtime.h>
#include <hip/hip_bf16.h>
#include <cstdint>

// B=4, L=2048, D=1024, H=16, DK=64
// R15 = exact revert to R13 (best green, 246.5us). exp2f (R14) was correct but
// SLOWER (libm guard code; not a bare v_exp_f32) — blacklisted with AND-mask.
// Pipeline: f32->bf16 converts, mask bitpack, GEMM1 (QKV proj, Q pre-scaled by
// 1/8, V written transposed, global_load_lds double-buffered staging),
// flash-attention (8-wave blocks, LDS-staged K/V, swapped QK^T, fixed m=0
// softmax via __expf, ones-MFMA denominator + masked popcount, setprio,
// cvt_pk P-pack), GEMM2 (+b2, f32 out).

typedef __attribute__((ext_vector_type(4))) float f32x4;
typedef __attribute__((ext_vector_type(8))) short s16x8;
typedef __attribute__((ext_vector_type(4))) short s16x4;
typedef __attribute__((ext_vector_type(4))) int   i32x4;

#define AS1 __attribute__((address_space(1)))
#define AS3 __attribute__((address_space(3)))

__device__ __forceinline__ short f2bf(float x) {
  unsigned u = __builtin_bit_cast(unsigned, x);
  unsigned r = u + 0x7fffu + ((u >> 16) & 1u);   // RNE
  return (short)(r >> 16);
}
__device__ __forceinline__ unsigned pack2(float a, float b) {
  // compiler-owned bf16x2 conversion; .x = low word, .y = high word.
  __hip_bfloat162 v = __float22bfloat162_rn(make_float2(a, b));
  unsigned r;
  __builtin_memcpy(&r, &v, 4);
  return r;
}

// ---------------- f32 -> bf16 elementwise (4/thread) ----------------
__global__ __launch_bounds__(256) void k_convert(const float* __restrict__ in,
                                                 short* __restrict__ out, int n4) {
  int i = blockIdx.x * 256 + threadIdx.x;
  if (i >= n4) return;
  float4 v = ((const float4*)in)[i];
  s16x4 o;
  o[0] = f2bf(v.x); o[1] = f2bf(v.y); o[2] = f2bf(v.z); o[3] = f2bf(v.w);
  ((s16x4*)out)[i] = o;
}

// ---------- transpose + convert: in (R x C) f32 -> out (C x R) bf16 ----------
__global__ __launch_bounds__(256) void k_transpose(const float* __restrict__ in,
                                                   short* __restrict__ out, int R, int C) {
  __shared__ float tile[32][33];
  int c0 = blockIdx.x * 32, r0 = blockIdx.y * 32;
  int tx = threadIdx.x, ty = threadIdx.y;     // block (32,8)
  #pragma unroll
  for (int k = 0; k < 32; k += 8)
    tile[ty + k][tx] = in[(size_t)(r0 + ty + k) * C + c0 + tx];
  __syncthreads();
  #pragma unroll
  for (int k = 0; k < 32; k += 8)
    out[(size_t)(c0 + ty + k) * R + r0 + tx] = f2bf(tile[tx][ty + k]);
}

// ---------------- mask (int32 0/1) -> bitmask via ballot ----------------
__global__ __launch_bounds__(256) void k_maskpack(const int* __restrict__ mask,
                                                  unsigned* __restrict__ bits) {
  int i = blockIdx.x * 256 + threadIdx.x;
  unsigned long long bal = __ballot(mask[i] != 0);
  int lane = threadIdx.x & 63;
  if (lane == 0)       bits[i >> 5] = (unsigned)bal;
  else if (lane == 32) bits[i >> 5] = (unsigned)(bal >> 32);
}

// ---------------- bf16 MFMA GEMM, A (MxK) row-major, Bt (NxK) row-major ------
// MODE 0: QKV projection -> bf16 out; cols <1024 (Q) scaled by 1/8 (exact),
//         cols <2048 to QKbuf, cols >=2048 to Vt transposed.
// MODE 1: output projection -> f32 out (d_out), +bias.
// Staging: global_load_lds width=16, pre-swizzled source chunk (attn-proven),
// double-buffered STAGE(next)->compute(cur)->barrier schedule.
template <int MODE>
__global__ __launch_bounds__(256, 2) void k_gemm(
    const short* __restrict__ A, const short* __restrict__ Bt,
    const float* __restrict__ bias,
    short* __restrict__ outQK, short* __restrict__ outVt,
    float* __restrict__ outF, int K, int N) {
  __shared__ short Ast[2][128 * 64];
  __shared__ short Bst[2][128 * 64];
  const int tid = threadIdx.x;
  const int lane = tid & 63;
  const int wv = tid >> 6;
  const int g = lane >> 4, c = lane & 15;
  const int m0 = blockIdx.x * 128, n0 = blockIdx.y * 128;
  const int wm = (wv & 1) * 64, wn = (wv >> 1) * 64;

  // staging: wave wv, iter p stages rows [p*32 + wv*8, +8); row&7 == rsub
  const int rsub = lane >> 3;                    // 0..7
  const int cp = (lane & 7) ^ rsub;              // pre-swizzled source chunk
  const short* aSrc = A  + (size_t)(m0 + wv * 8 + rsub) * K + cp * 8;
  const short* bSrc = Bt + (size_t)(n0 + wv * 8 + rsub) * K + cp * 8;

  auto STAGE = [&](int buf, int kt) {
    #pragma unroll
    for (int p = 0; p < 4; ++p) {
      __builtin_amdgcn_global_load_lds(
          (const AS1 void*)(aSrc + (size_t)(p * 32) * K + kt * 64),
          (AS3 void*)&Ast[buf][(p * 32 + wv * 8) * 64], 16, 0, 0);
      __builtin_amdgcn_global_load_lds(
          (const AS1 void*)(bSrc + (size_t)(p * 32) * K + kt * 64),
          (AS3 void*)&Bst[buf][(p * 32 + wv * 8) * 64], 16, 0, 0);
    }
  };

  f32x4 acc[4][4] = {};

  const int nkt = K >> 6;
  STAGE(0, 0);
  __syncthreads();

  #pragma unroll 1
  for (int kt = 0; kt < nkt; ++kt) {
    const int cur = kt & 1;
    if (kt + 1 < nkt) STAGE(cur ^ 1, kt + 1);
    #pragma unroll
    for (int s = 0; s < 2; ++s) {
      s16x8 aF[4], bF[4];
      #pragma unroll
      for (int mi = 0; mi < 4; ++mi) {
        int row = wm + mi * 16 + c;
        aF[mi] = *(const s16x8*)((const char*)&Ast[cur][0] + row * 128 +
                                 ((s * 64 + g * 16) ^ ((row & 7) << 4)));
      }
      #pragma unroll
      for (int ni = 0; ni < 4; ++ni) {
        int row = wn + ni * 16 + c;
        bF[ni] = *(const s16x8*)((const char*)&Bst[cur][0] + row * 128 +
                                 ((s * 64 + g * 16) ^ ((row & 7) << 4)));
      }
      #pragma unroll
      for (int mi = 0; mi < 4; ++mi)
        #pragma unroll
        for (int ni = 0; ni < 4; ++ni)
          acc[mi][ni] = __builtin_amdgcn_mfma_f32_16x16x32_bf16(
              aF[mi], bF[ni], acc[mi][ni], 0, 0, 0);
    }
    __syncthreads();   // drains vmcnt (next tile staged) + all waves done with cur
  }

  #pragma unroll
  for (int mi = 0; mi < 4; ++mi) {
    #pragma unroll
    for (int ni = 0; ni < 4; ++ni) {
      int colg = n0 + wn + ni * 16 + c;
      float bv = bias[colg];
      int rbase = m0 + wm + mi * 16 + 4 * g;   // 4 consecutive rows (4-aligned)
      if (MODE == 0) {
        float sc = (colg < 1024) ? 0.125f : 1.0f;   // fold 1/sqrt(dk) into Q
        if (colg < 2048) {
          #pragma unroll
          for (int r = 0; r < 4; ++r)
            outQK[(size_t)(rbase + r) * 2048 + colg] = f2bf((acc[mi][ni][r] + bv) * sc);
        } else {
          int j = colg - 2048;             // h*64+dk
          int bb = rbase >> 11, lq = rbase & 2047;
          s16x4 pk;
          #pragma unroll
          for (int r = 0; r < 4; ++r) pk[r] = f2bf(acc[mi][ni][r] + bv);
          *(s16x4*)(outVt + (size_t)((bb << 10) + j) * 2048 + lq) = pk;
        }
      } else {
        #pragma unroll
        for (int r = 0; r < 4; ++r)
          outF[(size_t)(rbase + r) * N + colg] = acc[mi][ni][r] + bv;
      }
    }
  }
}

// ---------------- flash attention: 8-wave blocks, shared K/V staging ---------
// Grid (L/128, H, B), 8 waves x 16 q-rows = 128 q-rows/block. K/V tiles staged
// double-buffered via global_load_lds (pre-swizzled source, rule #21); wave wv
// stages rows [wv*8, wv*8+8) = 1 instruction per buffer. S^T = mfma(K,Q):
// lane (c,g) holds S[q=c][k=16t+4g+r]. Fixed m=0 softmax; p_num = bt ?
// __expf(s) : 0 (select form — AND-mask convicted R9; exp2f slow, R14).
// Denominator = ones-MFMA rowsum + popcount(masked) (masked keys each
// contribute exp(0)=1, the torch-quirk semantics).
__global__ __launch_bounds__(512) void k_attn(
    const short* __restrict__ QK, const short* __restrict__ Vt,
    const unsigned* __restrict__ mbits, short* __restrict__ ctxb) {
  __shared__ short Klds[2][64 * 64];
  __shared__ short Vlds[2][64 * 64];
  __shared__ short Plds[8][16 * 64];
  const int tid = threadIdx.x;
  const int lane = tid & 63, wv = tid >> 6;      // wv = 0..7
  const int g = lane >> 4, c = lane & 15;
  const int b = blockIdx.z, h = blockIdx.y;
  const int qr = blockIdx.x * 128 + wv * 16;

  // staging: wave wv stages rows [wv*8, wv*8+8) of each tile (row&7 == rsub)
  const int r0 = wv * 8;
  const int rsub = lane >> 3;                    // 0..7
  const int cp = (lane & 7) ^ rsub;              // pre-swizzled source chunk
  const short* kSrc = QK + (size_t)(b * 2048 + r0 + rsub) * 2048 + 1024 + h * 64 + cp * 8;
  const short* vSrc = Vt + (size_t)((b * 16 + h) * 64 + r0 + rsub) * 2048 + cp * 8;

  auto STAGE = [&](int buf, int k0) {
    __builtin_amdgcn_global_load_lds((const AS1 void*)(kSrc + (size_t)k0 * 2048),
        (AS3 void*)&Klds[buf][r0 * 64], 16, 0, 0);
    __builtin_amdgcn_global_load_lds((const AS1 void*)(vSrc + k0),
        (AS3 void*)&Vlds[buf][r0 * 64], 16, 0, 0);
  };

  s16x8 qf[2];                                    // Q = B-operand fragments
  #pragma unroll
  for (int s = 0; s < 2; ++s)
    qf[s] = *(const s16x8*)(QK + (size_t)(b * 2048 + qr + c) * 2048 +
                            h * 64 + s * 32 + g * 8);

  const unsigned* mptr = mbits + (size_t)(b * 2048 + qr + c) * 64;

  // all-ones bf16 B-operand for the rowsum MFMA
  s16x8 ones;
  #pragma unroll
  for (int i = 0; i < 8; ++i) ones[i] = (short)0x3F80;

  int nm = 0;                       // masked count for q-row c (accumulated)
  f32x4 acc[4] = {};                // ctx[q=4g+r][d=16t+c]
  f32x4 accs = {};                  // rowsum[q=4g+r] of bf16 P (all c equal)
  char* pbase = (char*)&Plds[wv][0];
  const int sw = (c & 7) << 4;

  STAGE(0, 0);
  __syncthreads();

  #pragma unroll 1
  for (int it = 0; it < 32; ++it) {
    const int cur = it & 1;
    const int k0 = it * 64;
    if (it < 31) STAGE(cur ^ 1, k0 + 64);

    // ---- S^T = K Q^T : sf[t][r] = S[q=c][k=16t+4g+r] ----
    const char* kb = (const char*)&Klds[cur][0];
    f32x4 sf[4] = {};
    __builtin_amdgcn_s_setprio(1);
    #pragma unroll
    for (int t = 0; t < 4; ++t)
      #pragma unroll
      for (int s = 0; s < 2; ++s) {
        s16x8 kf = *(const s16x8*)(kb + (16 * t + c) * 128 + ((g * 16 + s * 64) ^ sw));
        sf[t] = __builtin_amdgcn_mfma_f32_16x16x32_bf16(kf, qf[s], sf[t], 0, 0, 0);
      }
    __builtin_amdgcn_s_setprio(0);

    // ---- mask bits for this lane's q-row (q = c) ----
    uint2 wd = *(const uint2*)(mptr + (k0 >> 5));
    nm += 64 - __popc(wd.x) - __popc(wd.y);      // masked keys this tile
    unsigned w0 = wd.x >> (4 * g), w1 = wd.y >> (4 * g);
    // ---- p_num = bt ? exp(s) : 0 ; masked handled via nm in denominator ----
    #pragma unroll
    for (int t = 0; t < 4; ++t) {
      unsigned w = (t < 2) ? w0 : w1;
      int sh = 16 * (t & 1);
      float p[4];
      #pragma unroll
      for (int r = 0; r < 4; ++r) {
        unsigned bt = (w >> (sh + r)) & 1u;
        p[r] = bt ? __expf(sf[t][r]) : 0.0f;     // masked -> 0 in numerator
      }
      unsigned lo = pack2(p[0], p[1]);
      unsigned hi = pack2(p[2], p[3]);
      *(uint2*)(pbase + c * 128 + ((t * 32 + g * 8) ^ sw)) = make_uint2(lo, hi);
    }
    asm volatile("" ::: "memory");   // keep P writes before P reads
    // ---- ctx += P V ; denom += P ones ----
    s16x8 pa[2];
    #pragma unroll
    for (int s = 0; s < 2; ++s)
      pa[s] = *(const s16x8*)(pbase + c * 128 + ((s * 64 + g * 16) ^ sw));
    const char* vb = (const char*)&Vlds[cur][0];
    __builtin_amdgcn_s_setprio(1);
    accs = __builtin_amdgcn_mfma_f32_16x16x32_bf16(pa[0], ones, accs, 0, 0, 0);
    accs = __builtin_amdgcn_mfma_f32_16x16x32_bf16(pa[1], ones, accs, 0, 0, 0);
    #pragma unroll
    for (int t = 0; t < 4; ++t)
      #pragma unroll
      for (int s = 0; s < 2; ++s) {
        s16x8 vf = *(const s16x8*)(vb + (16 * t + c) * 128 + ((g * 16 + s * 64) ^ sw));
        acc[t] = __builtin_amdgcn_mfma_f32_16x16x32_bf16(pa[s], vf, acc[t], 0, 0, 0);
      }
    __builtin_amdgcn_s_setprio(0);
    __syncthreads();   // drains vmcnt (next tile staged) + all waves done with cur
  }

  // ---- epilogue: denom[q=4g+r] = accs[r] + nm(from lane q=4g+r) ----
  float nmf = (float)nm;
  float lv[4];
  #pragma unroll
  for (int r = 0; r < 4; ++r)
    lv[r] = 1.0f / (accs[r] + __shfl(nmf, 4 * g + r));
  #pragma unroll
  for (int t = 0; t < 4; ++t)
    #pragma unroll
    for (int r = 0; r < 4; ++r)
      ctxb[(size_t)(b * 2048 + qr + 4 * g + r) * 1024 + h * 64 + t * 16 + c] =
          f2bf(acc[t][r] * lv[r]);
}

extern "C" void kernel_launch(void* const* d_in, const int* in_sizes, int n_in,
                              void* d_out, int out_size, void* d_ws, size_t ws_size,
                              hipStream_t stream) {
  const float* inputs = (const float*)d_in[0];   // (4,2048,1024) f32
  const int*   mask   = (const int*)  d_in[1];   // (4,2048,2048) int32
  const float* W1     = (const float*)d_in[2];   // (1024,3072) f32
  const float* b1     = (const float*)d_in[3];   // (3072,) f32
  const float* W2     = (const float*)d_in[4];   // (1024,1024) f32
  const float* b2     = (const float*)d_in[5];   // (1024,) f32
  float* out = (float*)d_out;                    // (4,2048,1024) f32

  char* ws = (char*)d_ws;
  short* Xbf = (short*)ws;        ws += (size_t)8192 * 1024 * 2;   // 16.78 MB
  short* W1t = (short*)ws;        ws += (size_t)3072 * 1024 * 2;   //  6.29 MB
  short* W2t = (short*)ws;        ws += (size_t)1024 * 1024 * 2;   //  2.10 MB
  short* QKb = (short*)ws;        ws += (size_t)8192 * 2048 * 2;   // 33.55 MB
  short* Vtb = (short*)ws;        ws += (size_t)4096 * 2048 * 2;   // 16.78 MB
  short* Ctx = (short*)ws;        ws += (size_t)8192 * 1024 * 2;   // 16.78 MB
  unsigned* mbits = (unsigned*)ws; ws += (size_t)4 * 2048 * 64 * 4; // 2.10 MB
  // total ~94.4 MB of d_ws

  k_convert<<<8192, 256, 0, stream>>>(inputs, Xbf, 2097152);
  k_transpose<<<dim3(96, 32), dim3(32, 8), 0, stream>>>(W1, W1t, 1024, 3072);
  k_transpose<<<dim3(32, 32), dim3(32, 8), 0, stream>>>(W2, W2t, 1024, 1024);
  k_gemm<0><<<dim3(64, 24), 256, 0, stream>>>(Xbf, W1t, b1, QKb, Vtb, nullptr,
                                              1024, 3072);
  k_maskpack<<<65536, 256, 0, stream>>>(mask, mbits);
  k_attn<<<dim3(16, 16, 4), 512, 0, stream>>>(QKb, Vtb, mbits, Ctx);
  k_gemm<1><<<dim3(64, 8), 256, 0, stream>>>(Ctx, W2t, b2, nullptr, nullptr, out,
                                             1024, 1024);
}